// Round 2
// baseline (4470.139 us; speedup 1.0000x reference)
//
#include <hip/hip_runtime.h>

// Seq2Seq LSTM (2-layer enc + 2-layer dec, teacher forcing) + vocab projection.
// Round 2: dtype-adaptive. A device-side probe classifies the float inputs as
// bf16 vs fp32 (round 1 NaN is consistent with fp32 data read as bf16 pairs:
// random low-mantissa u16s hit bf16 NaN encodings). All external float loads
// go through templated loaders; internal state (y/h bf16, c fp32) unchanged.
// Projection GEMM is two named kernels (one per dtype, inactive early-outs)
// so rocprof reveals the true dtype for round 3.

#define BATCH 32
#define T 64
#define HID 512
#define VOCAB 32000
#define BOS 1

typedef unsigned short u16;
typedef unsigned int u32;
typedef __attribute__((ext_vector_type(8))) short bf16x8;
typedef __attribute__((ext_vector_type(4))) float f32x4;

__device__ __forceinline__ float bf2f(u16 u) {
  return __uint_as_float(((u32)u) << 16);
}
__device__ __forceinline__ short f2bfs(float f) {
  u32 x = __float_as_uint(f);
  u32 r = x + 0x7fffu + ((x >> 16) & 1u);   // RNE; no NaNs in this workload
  return (short)(r >> 16);
}

// Load 8 consecutive external-float elements as bf16x8.
template<bool BF16>
__device__ __forceinline__ bf16x8 ldext8(const void* base, size_t off) {
  if constexpr (BF16) {
    return *(const bf16x8*)((const u16*)base + off);
  } else {
    const float* p = (const float*)base + off;
    float4 a = *(const float4*)p;
    float4 b = *(const float4*)(p + 4);
    bf16x8 r;
    r[0] = f2bfs(a.x); r[1] = f2bfs(a.y); r[2] = f2bfs(a.z); r[3] = f2bfs(a.w);
    r[4] = f2bfs(b.x); r[5] = f2bfs(b.y); r[6] = f2bfs(b.z); r[7] = f2bfs(b.w);
    return r;
  }
}
template<bool BF16>
__device__ __forceinline__ float ldext1(const void* base, size_t off) {
  if constexpr (BF16) return bf2f(((const u16*)base)[off]);
  else return ((const float*)base)[off];
}

// ---------------- dtype probe: low u16 of each u32 is a bf16 value (clustered
// exponent) for bf16 data, uniform mantissa bits for fp32 data.
__global__ void dtype_probe(const u32* __restrict__ w, int* __restrict__ flag) {
  __shared__ int cnt;
  if (threadIdx.x == 0) cnt = 0;
  __syncthreads();
  int c = 0;
  for (int i = threadIdx.x; i < 1024; i += 256) {
    u16 lo = (u16)(w[i] & 0xFFFFu);
    int e = (lo >> 7) & 0xFF;                 // bf16 exponent field
    if (e >= 0x68 && e <= 0x7E) c++;          // |v| in [2^-23, 1.0)
  }
  atomicAdd(&cnt, c);
  __syncthreads();
  if (threadIdx.x == 0) *flag = (cnt > 512) ? 1 : 0;   // 1 => bf16
}

struct Slot {
  const void* Wih;    // [2048][512] external float
  const void* Whh;    // [2048][512] external float
  const void* bias;   // [2048]      external float
  const int* tokens;  // [B][T] (token path) or null
  const void* emb;    // [V][512] external float (token path)
  const u16* x_in;    // [T][B][512] internal bf16 (y of previous layer)
  const u16* h_in;    // [B][512] internal bf16 (y[t-1] or zeros)
  u16* y_out;         // [B][512] internal bf16 (= y[t] = h_t)
  float* c;           // [B][512] fp32
  int t;              // step; <0 => skip this slot
  int shift;          // 1: decoder input shift (t==0 -> BOS else tgt[t-1])
};

template<bool BF16>
__device__ __forceinline__ void step_body(const Slot& s, float (*gsh)[16][34]) {
  const int tid = threadIdx.x;
  const int lane = tid & 63;
  const int w = tid >> 6;           // wave index == gate index (i,f,g,o)
  const int j0 = blockIdx.x * 16;   // hidden-unit group
  const int fr = lane & 15;
  const int q8 = (lane >> 4) * 8;

  f32x4 acc0 = {0.f, 0.f, 0.f, 0.f};
  f32x4 acc1 = {0.f, 0.f, 0.f, 0.f};

  const int grow = w * HID + j0 + fr;          // this lane's gate row (B operand)
  const size_t wr = (size_t)grow * HID;

  if (s.tokens) {                              // layer-0: gather embedding rows
    int t0, t1;
    if (s.shift) {
      t0 = (s.t == 0) ? BOS : s.tokens[fr * T + s.t - 1];
      t1 = (s.t == 0) ? BOS : s.tokens[(fr + 16) * T + s.t - 1];
    } else {
      t0 = s.tokens[fr * T + s.t];
      t1 = s.tokens[(fr + 16) * T + s.t];
    }
    const size_t e0 = (size_t)t0 * HID, e1 = (size_t)t1 * HID;
#pragma unroll 4
    for (int ks = 0; ks < HID; ks += 32) {
      bf16x8 bfrag = ldext8<BF16>(s.Wih, wr + ks + q8);
      bf16x8 a0 = ldext8<BF16>(s.emb, e0 + ks + q8);
      bf16x8 a1 = ldext8<BF16>(s.emb, e1 + ks + q8);
      acc0 = __builtin_amdgcn_mfma_f32_16x16x32_bf16(a0, bfrag, acc0, 0, 0, 0);
      acc1 = __builtin_amdgcn_mfma_f32_16x16x32_bf16(a1, bfrag, acc1, 0, 0, 0);
    }
  } else {                                     // layer-1: previous layer y (bf16)
    const u16* xb = s.x_in + (size_t)s.t * (BATCH * HID);
#pragma unroll 4
    for (int ks = 0; ks < HID; ks += 32) {
      bf16x8 bfrag = ldext8<BF16>(s.Wih, wr + ks + q8);
      bf16x8 a0 = *(const bf16x8*)(xb + fr * HID + ks + q8);
      bf16x8 a1 = *(const bf16x8*)(xb + (fr + 16) * HID + ks + q8);
      acc0 = __builtin_amdgcn_mfma_f32_16x16x32_bf16(a0, bfrag, acc0, 0, 0, 0);
      acc1 = __builtin_amdgcn_mfma_f32_16x16x32_bf16(a1, bfrag, acc1, 0, 0, 0);
    }
  }

  // h @ Whh^T (h always internal bf16)
#pragma unroll 4
  for (int ks = 0; ks < HID; ks += 32) {
    bf16x8 bfrag = ldext8<BF16>(s.Whh, wr + ks + q8);
    bf16x8 a0 = *(const bf16x8*)(s.h_in + fr * HID + ks + q8);
    bf16x8 a1 = *(const bf16x8*)(s.h_in + (fr + 16) * HID + ks + q8);
    acc0 = __builtin_amdgcn_mfma_f32_16x16x32_bf16(a0, bfrag, acc0, 0, 0, 0);
    acc1 = __builtin_amdgcn_mfma_f32_16x16x32_bf16(a1, bfrag, acc1, 0, 0, 0);
  }

  // D layout: col(=hidden jj)=lane&15, row(=batch)=(lane>>4)*4+reg
  const int rq = (lane >> 4) * 4;
#pragma unroll
  for (int r = 0; r < 4; ++r) {
    gsh[w][fr][rq + r] = acc0[r];        // batches 0..15
    gsh[w][fr][16 + rq + r] = acc1[r];   // batches 16..31
  }
  __syncthreads();

  // cell update: 512 (b, j) states, 2 per thread
#pragma unroll
  for (int u = 0; u < 2; ++u) {
    int sidx = tid * 2 + u;
    int bb = sidx & 31;
    int jj = sidx >> 5;                  // 0..15
    int j = j0 + jj;
    float gi = gsh[0][jj][bb] + ldext1<BF16>(s.bias, j);
    float gf = gsh[1][jj][bb] + ldext1<BF16>(s.bias, HID + j);
    float gg = gsh[2][jj][bb] + ldext1<BF16>(s.bias, 2 * HID + j);
    float go = gsh[3][jj][bb] + ldext1<BF16>(s.bias, 3 * HID + j);
    float* cp = s.c + bb * HID + j;
    float cold = *cp;
    float si = 1.f / (1.f + __expf(-gi));
    float sf = 1.f / (1.f + __expf(-gf));
    float so = 1.f / (1.f + __expf(-go));
    float cn = sf * cold + si * tanhf(gg);
    *cp = cn;
    s.y_out[bb * HID + j] = (u16)f2bfs(so * tanhf(cn));
  }
}

__global__ __launch_bounds__(256) void lstm_step(Slot s0, Slot s1,
                                                 const int* __restrict__ flag) {
  __shared__ float gsh[4][16][34];
  Slot s = (blockIdx.z == 0) ? s0 : s1;
  if (s.t < 0) return;
  if (*flag) step_body<true>(s, gsh);
  else       step_body<false>(s, gsh);
}

// ---------------- projection GEMM: out[b][t][v] = u2[t][b][:] . lin_W[v][:] + lin_b[v]
template<bool BF16>
__device__ __forceinline__ void out_gemm_body(const u16* __restrict__ A,   // [2048][512] bf16 internal
                                              const void* __restrict__ Wv, // [32000][512] external
                                              const void* __restrict__ bias,
                                              void* __restrict__ out) {
  __shared__ __align__(16) u16 As[128 * 40];
  __shared__ __align__(16) u16 Bs[128 * 40];
  const int tid = threadIdx.x;
  const int lane = tid & 63;
  const int wv = tid >> 6;
  const int wm = wv >> 1, wn = wv & 1;
  const int m0 = blockIdx.y * 128;
  const int n0 = blockIdx.x * 128;
  const int fr = lane & 15, q8 = (lane >> 4) * 8;
  const int r0 = tid >> 2;           // 0..63
  const int c8 = (tid & 3) * 8;      // 0,8,16,24

  f32x4 acc[4][4] = {};

  for (int k0 = 0; k0 < 512; k0 += 32) {
    __syncthreads();
    *(uint4*)&As[r0 * 40 + c8]        = *(const uint4*)&A[(size_t)(m0 + r0) * 512 + k0 + c8];
    *(uint4*)&As[(r0 + 64) * 40 + c8] = *(const uint4*)&A[(size_t)(m0 + r0 + 64) * 512 + k0 + c8];
    *(bf16x8*)&Bs[r0 * 40 + c8]        = ldext8<BF16>(Wv, (size_t)(n0 + r0) * 512 + k0 + c8);
    *(bf16x8*)&Bs[(r0 + 64) * 40 + c8] = ldext8<BF16>(Wv, (size_t)(n0 + r0 + 64) * 512 + k0 + c8);
    __syncthreads();
    bf16x8 af[4], bg[4];
#pragma unroll
    for (int i = 0; i < 4; ++i) {
      af[i] = *(const bf16x8*)&As[(wm * 64 + i * 16 + fr) * 40 + q8];
      bg[i] = *(const bf16x8*)&Bs[(wn * 64 + i * 16 + fr) * 40 + q8];
    }
#pragma unroll
    for (int i = 0; i < 4; ++i)
#pragma unroll
      for (int j = 0; j < 4; ++j)
        acc[i][j] = __builtin_amdgcn_mfma_f32_16x16x32_bf16(af[i], bg[j], acc[i][j], 0, 0, 0);
  }

  const int cl = lane & 15;
  const int rq = (lane >> 4) * 4;
#pragma unroll
  for (int j = 0; j < 4; ++j) {
    int n = n0 + wn * 64 + j * 16 + cl;
    float bv = ldext1<BF16>(bias, n);
#pragma unroll
    for (int i = 0; i < 4; ++i) {
#pragma unroll
      for (int r = 0; r < 4; ++r) {
        int m = m0 + wm * 64 + i * 16 + rq + r;
        int tt = m >> 5, bb = m & 31;
        size_t oidx = ((size_t)bb * T + tt) * VOCAB + n;
        float v = acc[i][j][r] + bv;
        if constexpr (BF16) ((u16*)out)[oidx] = (u16)f2bfs(v);
        else                ((float*)out)[oidx] = v;
      }
    }
  }
}

__global__ __launch_bounds__(256) void out_gemm_bf16(const u16* A, const void* Wv,
                                                     const void* bias, void* out,
                                                     const int* __restrict__ flag) {
  if (!*flag) return;
  out_gemm_body<true>(A, Wv, bias, out);
}
__global__ __launch_bounds__(256) void out_gemm_f32(const u16* A, const void* Wv,
                                                    const void* bias, void* out,
                                                    const int* __restrict__ flag) {
  if (*flag) return;
  out_gemm_body<false>(A, Wv, bias, out);
}

__global__ void init_state(u16* hz, float* c0, float* c1) {
  int i = blockIdx.x * 256 + threadIdx.x;   // 64*256 == 16384 == BATCH*HID
  hz[i] = 0;
  c0[i] = 0.f;
  c1[i] = 0.f;
}

extern "C" void kernel_launch(void* const* d_in, const int* in_sizes, int n_in,
                              void* d_out, int out_size, void* d_ws, size_t ws_size,
                              hipStream_t stream) {
  (void)in_sizes; (void)n_in; (void)out_size; (void)ws_size;
  const int* x = (const int*)d_in[0];
  const int* tgt = (const int*)d_in[1];
  const void* enc_emb = d_in[2];
  const void* dec_emb = d_in[3];
  const void* Wih[4] = {d_in[4], d_in[7], d_in[10], d_in[13]};
  const void* Whh[4] = {d_in[5], d_in[8], d_in[11], d_in[14]};
  const void* bias[4] = {d_in[6], d_in[9], d_in[12], d_in[15]};
  const void* lin_W = d_in[16];
  const void* lin_b = d_in[17];

  char* ws = (char*)d_ws;
  u16* y_e0 = (u16*)(ws);                 // [T][B][H] bf16, 2MB each
  u16* y_e1 = (u16*)(ws + 0x200000);
  u16* y_d0 = (u16*)(ws + 0x400000);
  u16* y_d1 = (u16*)(ws + 0x600000);      // == u2 == GEMM A
  u16* h_zero = (u16*)(ws + 0x800000);    // [B][H] bf16 zeros
  float* c0 = (float*)(ws + 0x810000);    // [B][H] fp32 (layer0 chain: e0 -> d0)
  float* c1 = (float*)(ws + 0x820000);    // [B][H] fp32 (layer1 chain: e1 -> d1)
  int* flag = (int*)(ws + 0x830000);      // 1 => external floats are bf16

  dtype_probe<<<dim3(1), 256, 0, stream>>>((const u32*)lin_W, flag);
  init_state<<<dim3(64), 256, 0, stream>>>(h_zero, c0, c1);

  const int NB = BATCH * HID;

  // encoder (layers e0, e1 pipelined diagonally)
  for (int k = 0; k <= T; ++k) {
    Slot s0 = {}; s0.t = -1;
    Slot s1 = {}; s1.t = -1;
    if (k < T) {
      s0.Wih = Wih[0]; s0.Whh = Whh[0]; s0.bias = bias[0];
      s0.tokens = x; s0.emb = enc_emb; s0.shift = 0;
      s0.h_in = (k == 0) ? h_zero : y_e0 + (size_t)(k - 1) * NB;
      s0.y_out = y_e0 + (size_t)k * NB;
      s0.c = c0; s0.t = k;
    }
    if (k >= 1) {
      int t = k - 1;
      s1.Wih = Wih[1]; s1.Whh = Whh[1]; s1.bias = bias[1];
      s1.x_in = y_e0;
      s1.h_in = (t == 0) ? h_zero : y_e1 + (size_t)(t - 1) * NB;
      s1.y_out = y_e1 + (size_t)t * NB;
      s1.c = c1; s1.t = t;
    }
    lstm_step<<<dim3(32, 1, 2), 256, 0, stream>>>(s0, s1, flag);
  }

  // decoder (d0 seeded by e0 finals, d1 by e1 finals; c buffers carry over)
  for (int k = 0; k <= T; ++k) {
    Slot s0 = {}; s0.t = -1;
    Slot s1 = {}; s1.t = -1;
    if (k < T) {
      s0.Wih = Wih[2]; s0.Whh = Whh[2]; s0.bias = bias[2];
      s0.tokens = tgt; s0.emb = dec_emb; s0.shift = 1;
      s0.h_in = (k == 0) ? y_e0 + (size_t)(T - 1) * NB : y_d0 + (size_t)(k - 1) * NB;
      s0.y_out = y_d0 + (size_t)k * NB;
      s0.c = c0; s0.t = k;
    }
    if (k >= 1) {
      int t = k - 1;
      s1.Wih = Wih[3]; s1.Whh = Whh[3]; s1.bias = bias[3];
      s1.x_in = y_d0;
      s1.h_in = (t == 0) ? y_e1 + (size_t)(T - 1) * NB : y_d1 + (size_t)(t - 1) * NB;
      s1.y_out = y_d1 + (size_t)t * NB;
      s1.c = c1; s1.t = t;
    }
    lstm_step<<<dim3(32, 1, 2), 256, 0, stream>>>(s0, s1, flag);
  }

  out_gemm_bf16<<<dim3(250, 16), 256, 0, stream>>>(y_d1, lin_W, lin_b, d_out, flag);
  out_gemm_f32 <<<dim3(250, 16), 256, 0, stream>>>(y_d1, lin_W, lin_b, d_out, flag);
}